// Round 5
// baseline (204.932 us; speedup 1.0000x reference)
//
#include <hip/hip_runtime.h>

#define N_VOX 32768
#define EPSV 1e-5f

typedef __attribute__((ext_vector_type(8))) short bfrag;
typedef __attribute__((ext_vector_type(4))) float ffrag;

__device__ __forceinline__ float bf2f_lo(unsigned int u) {
    union { unsigned int i; float f; } c; c.i = u << 16; return c.f;
}
__device__ __forceinline__ float bf2f_hi(unsigned int u) {
    union { unsigned int i; float f; } c; c.i = u & 0xFFFF0000u; return c.f;
}
__device__ __forceinline__ unsigned short f2bf(float f) {
    union { float f; unsigned int i; } c; c.f = f;
    unsigned int i = c.i;
    return (unsigned short)((i + 0x7FFFu + ((i >> 16) & 1u)) >> 16);
}
__device__ __forceinline__ bfrag pack8(float4 a, float4 b) {
    bfrag r;
    r[0] = (short)f2bf(a.x); r[1] = (short)f2bf(a.y);
    r[2] = (short)f2bf(a.z); r[3] = (short)f2bf(a.w);
    r[4] = (short)f2bf(b.x); r[5] = (short)f2bf(b.y);
    r[6] = (short)f2bf(b.z); r[7] = (short)f2bf(b.w);
    return r;
}

// -------- Kernel 1: fused LayerNorm + QKV GEMM --------
// Block = 32 voxels. One barrier after LN; then waves independent:
// B-fragments straight from global fp32 qkv_w (L2-hot), converted in-reg.
__global__ __launch_bounds__(256) void ln_qkv_kernel(const float* __restrict__ x,
                                                     const float* __restrict__ gamma,
                                                     const float* __restrict__ beta,
                                                     const float* __restrict__ w,
                                                     const float* __restrict__ bias,
                                                     unsigned short* __restrict__ qkv) {
    __shared__ __align__(16) unsigned short a_s[32 * 136];  // 8.5 KB
    __shared__ float xs[128 * 33];                          // 16.9 KB
    __shared__ float g[128], bta[128];
    __shared__ float ps[256], pq[256];
    __shared__ float muS[32], rsS[32];

    int t = threadIdx.x;
    int v0 = blockIdx.x * 32;
    if (t < 128) { g[t] = gamma[t]; bta[t] = beta[t]; }
    int vv = t & 31, cq = t >> 5;           // cq in [0,8)
    #pragma unroll
    for (int cb = 0; cb < 16; cb++) {
        int c = cb * 8 + cq;
        xs[c * 33 + vv] = x[(size_t)c * N_VOX + v0 + vv];
    }
    __syncthreads();
    float s = 0.f, sq = 0.f;
    #pragma unroll
    for (int i = 0; i < 16; i++) {
        float val = xs[(cq * 16 + i) * 33 + vv];
        s += val; sq += val * val;
    }
    ps[t] = s; pq[t] = sq;
    __syncthreads();
    if (t < 32) {
        float S = 0.f, Q = 0.f;
        #pragma unroll
        for (int k = 0; k < 8; k++) { S += ps[t + k * 32]; Q += pq[t + k * 32]; }
        float mu = S * (1.0f / 128.0f);
        float var = Q * (1.0f / 128.0f) - mu * mu;
        muS[t] = mu; rsS[t] = rsqrtf(var + EPSV);
    }
    __syncthreads();
    {
        int c8 = t & 15;
        #pragma unroll
        for (int pass = 0; pass < 2; pass++) {
            int v = pass * 16 + (t >> 4);
            float mu = muS[v], rs = rsS[v];
            union { unsigned short u[8]; uint4 q; } pk;
            #pragma unroll
            for (int i = 0; i < 8; i++) {
                int c = c8 * 8 + i;
                float val = (xs[c * 33 + v] - mu) * rs * g[c] + bta[c];
                pk.u[i] = f2bf(val);
            }
            *(uint4*)&a_s[v * 136 + c8 * 8] = pk.q;
        }
    }
    __syncthreads();   // only barrier before independent wave work

    int wave = t >> 6, lane = t & 63, m = lane & 15, quad = lane >> 4;
    int msub = wave & 1;            // which 16-voxel half of the block
    int sgrp = wave >> 1;           // strip group: 0 -> strips 0-2, 1 -> 3-5

    for (int it = 0; it < 3; it++) {
        int o0 = (sgrp * 3 + it) * 64;
        ffrag acc[4] = {ffrag{0,0,0,0}, ffrag{0,0,0,0}, ffrag{0,0,0,0}, ffrag{0,0,0,0}};
        #pragma unroll
        for (int kk = 0; kk < 4; kk++) {
            bfrag a = *(bfrag*)&a_s[(msub * 16 + m) * 136 + kk * 32 + quad * 8];
            #pragma unroll
            for (int nt = 0; nt < 4; nt++) {
                const float* wr = &w[(size_t)(o0 + nt * 16 + m) * 128 + kk * 32 + quad * 8];
                bfrag bb = pack8(*(const float4*)wr, *(const float4*)(wr + 4));
                acc[nt] = __builtin_amdgcn_mfma_f32_16x16x32_bf16(a, bb, acc[nt], 0, 0, 0);
            }
        }
        #pragma unroll
        for (int nt = 0; nt < 4; nt++) {
            int o = o0 + nt * 16 + m;
            float bs = bias[o];
            int sec = o >> 7;
            int oc = o & 127;
            unsigned short* dst = qkv + (size_t)sec * ((size_t)N_VOX * 128);
            #pragma unroll
            for (int r = 0; r < 4; r++) {
                int vg = v0 + msub * 16 + quad * 4 + r;
                dst[(size_t)vg * 128 + oc] = f2bf(acc[nt][r] + bs);
            }
        }
    }
}

// -------- Kernel 2: fused neighborhood attention + proj + residual --------
// Block = 16 z-consecutive voxels, 4 waves. Attn: wave w owns voxels w*4..w*4+3,
// processed as 2 interleaved pairs (2 channels/lane packed). Result -> LDS.
// Proj: MFMA 16x16x32, A from LDS, B converted in-reg from fp32 proj_w.
__global__ __launch_bounds__(256) void attn_proj_kernel(const unsigned int* __restrict__ qb,
                                                        const unsigned int* __restrict__ kb,
                                                        const unsigned int* __restrict__ vb,
                                                        const float* __restrict__ w,
                                                        const float* __restrict__ bias,
                                                        const float* __restrict__ xres,
                                                        float* __restrict__ out) {
    __shared__ __align__(16) unsigned short att_s[16 * 136];
    int t = threadIdx.x;
    int wave = t >> 6, lane = t & 63;
    int v0 = blockIdx.x * 16;
    const float scale = 0.17677669529663687f; // 32^-0.5

    for (int p = 0; p < 2; p++) {
        int vA = v0 + wave * 4 + p * 2;   // even offset -> vB=vA+1 shares x,y
        int vB = vA + 1;
        int zA = vA & 31, yA = (vA >> 5) & 31, xA = vA >> 10;
        int baseA = (min(max(xA - 1, 0), 29) << 10) + (min(max(yA - 1, 0), 29) << 5)
                  + min(max(zA - 1, 0), 29);
        int zB = vB & 31;
        int baseB = (min(max(xA - 1, 0), 29) << 10) + (min(max(yA - 1, 0), 29) << 5)
                  + min(max(zB - 1, 0), 29);
        unsigned int qpA = qb[(size_t)vA * 64 + lane];
        unsigned int qpB = qb[(size_t)vB * 64 + lane];
        float qA0 = bf2f_lo(qpA) * scale, qA1 = bf2f_hi(qpA) * scale;
        float qB0 = bf2f_lo(qpB) * scale, qB1 = bf2f_hi(qpB) * scale;
        float sA[27], sB[27];
        unsigned int vpA[27], vpB[27];
        #pragma unroll
        for (int j = 0; j < 27; j++) {
            int off = ((j / 9) << 10) + (((j % 9) / 3) << 5) + (j % 3);
            size_t iA = (size_t)(baseA + off) * 64 + lane;
            size_t iB = (size_t)(baseB + off) * 64 + lane;
            unsigned int kA = kb[iA], kB = kb[iB];
            vpA[j] = vb[iA]; vpB[j] = vb[iB];
            float pA = qA0 * bf2f_lo(kA) + qA1 * bf2f_hi(kA);
            float pB = qB0 * bf2f_lo(kB) + qB1 * bf2f_hi(kB);
            pA += __shfl_xor(pA, 8);  pB += __shfl_xor(pB, 8);
            pA += __shfl_xor(pA, 4);  pB += __shfl_xor(pB, 4);
            pA += __shfl_xor(pA, 2);  pB += __shfl_xor(pB, 2);
            pA += __shfl_xor(pA, 1);  pB += __shfl_xor(pB, 1);
            sA[j] = pA; sB[j] = pB;
        }
        float mA = sA[0], mB = sB[0];
        #pragma unroll
        for (int j = 1; j < 27; j++) { mA = fmaxf(mA, sA[j]); mB = fmaxf(mB, sB[j]); }
        float suA = 0.f, suB = 0.f;
        #pragma unroll
        for (int j = 0; j < 27; j++) {
            sA[j] = __expf(sA[j] - mA); suA += sA[j];
            sB[j] = __expf(sB[j] - mB); suB += sB[j];
        }
        float ivA = 1.0f / suA, ivB = 1.0f / suB;
        float oA0 = 0.f, oA1 = 0.f, oB0 = 0.f, oB1 = 0.f;
        #pragma unroll
        for (int j = 0; j < 27; j++) {
            oA0 += sA[j] * bf2f_lo(vpA[j]); oA1 += sA[j] * bf2f_hi(vpA[j]);
            oB0 += sB[j] * bf2f_lo(vpB[j]); oB1 += sB[j] * bf2f_hi(vpB[j]);
        }
        unsigned int pkA = ((unsigned int)f2bf(oA0 * ivA)) | (((unsigned int)f2bf(oA1 * ivA)) << 16);
        unsigned int pkB = ((unsigned int)f2bf(oB0 * ivB)) | (((unsigned int)f2bf(oB1 * ivB)) << 16);
        int vloc = wave * 4 + p * 2;
        *(unsigned int*)&att_s[vloc * 136 + lane * 2] = pkA;
        *(unsigned int*)&att_s[(vloc + 1) * 136 + lane * 2] = pkB;
    }
    __syncthreads();

    // proj phase: wave w handles output-channel tiles 2w, 2w+1
    int m = lane & 15, quad = lane >> 4;
    ffrag acc0 = ffrag{0,0,0,0}, acc1 = ffrag{0,0,0,0};
    #pragma unroll
    for (int kk = 0; kk < 4; kk++) {
        bfrag a = *(bfrag*)&att_s[m * 136 + kk * 32 + quad * 8];
        const float* wr0 = &w[(size_t)((wave * 2 + 0) * 16 + m) * 128 + kk * 32 + quad * 8];
        const float* wr1 = &w[(size_t)((wave * 2 + 1) * 16 + m) * 128 + kk * 32 + quad * 8];
        bfrag b0 = pack8(*(const float4*)wr0, *(const float4*)(wr0 + 4));
        bfrag b1 = pack8(*(const float4*)wr1, *(const float4*)(wr1 + 4));
        acc0 = __builtin_amdgcn_mfma_f32_16x16x32_bf16(a, b0, acc0, 0, 0, 0);
        acc1 = __builtin_amdgcn_mfma_f32_16x16x32_bf16(a, b1, acc1, 0, 0, 0);
    }
    #pragma unroll
    for (int nt = 0; nt < 2; nt++) {
        ffrag acc = nt ? acc1 : acc0;
        int c = (wave * 2 + nt) * 16 + m;
        float bs = bias[c];
        int vg = v0 + quad * 4;
        float4 r = *(const float4*)&xres[(size_t)c * N_VOX + vg];
        float4 ov;
        ov.x = acc[0] + bs + r.x;
        ov.y = acc[1] + bs + r.y;
        ov.z = acc[2] + bs + r.z;
        ov.w = acc[3] + bs + r.w;
        *(float4*)&out[(size_t)c * N_VOX + vg] = ov;
    }
}

extern "C" void kernel_launch(void* const* d_in, const int* in_sizes, int n_in,
                              void* d_out, int out_size, void* d_ws, size_t ws_size,
                              hipStream_t stream) {
    const float* x      = (const float*)d_in[0];
    const float* gamma  = (const float*)d_in[1];
    const float* beta   = (const float*)d_in[2];
    const float* qkv_w  = (const float*)d_in[3];
    const float* qkv_b  = (const float*)d_in[4];
    const float* proj_w = (const float*)d_in[5];
    const float* proj_b = (const float*)d_in[6];
    float* out = (float*)d_out;

    unsigned short* qkv = (unsigned short*)d_ws;           // q|k|v, 8 MB each
    const unsigned short* qb = qkv;
    const unsigned short* kb = qkv + (size_t)N_VOX * 128;
    const unsigned short* vb = qkv + (size_t)2 * N_VOX * 128;

    hipLaunchKernelGGL(ln_qkv_kernel, dim3(1024), dim3(256), 0, stream,
                       x, gamma, beta, qkv_w, qkv_b, qkv);
    hipLaunchKernelGGL(attn_proj_kernel, dim3(2048), dim3(256), 0, stream,
                       (const unsigned int*)qb, (const unsigned int*)kb,
                       (const unsigned int*)vb, proj_w, proj_b, x, out);
}

// Round 6
// 162.338 us; speedup vs baseline: 1.2624x; 1.2624x over previous
//
#include <hip/hip_runtime.h>

#define N_VOX 32768
#define EPSV 1e-5f
#define SCALE 0.17677669529663687f  // 32^-0.5

typedef __attribute__((ext_vector_type(8))) short bfrag;
typedef __attribute__((ext_vector_type(4))) float ffrag;

__device__ __forceinline__ float bf2f_lo(unsigned int u) {
    union { unsigned int i; float f; } c; c.i = u << 16; return c.f;
}
__device__ __forceinline__ float bf2f_hi(unsigned int u) {
    union { unsigned int i; float f; } c; c.i = u & 0xFFFF0000u; return c.f;
}
__device__ __forceinline__ unsigned short f2bf(float f) {
    union { float f; unsigned int i; } c; c.f = f;
    unsigned int i = c.i;
    return (unsigned short)((i + 0x7FFFu + ((i >> 16) & 1u)) >> 16);
}

// -------- Kernel 0: convert weights fp32 -> bf16 once; fold SCALE into q rows --------
// wq: 384x128 (rows 0-127 scaled), wp: 128x128, bias_s[384] = qkv_b * (row<128 ? SCALE : 1)
__global__ __launch_bounds__(256) void convw_kernel(const float* __restrict__ qkv_w,
                                                    const float* __restrict__ proj_w,
                                                    const float* __restrict__ qkv_b,
                                                    unsigned short* __restrict__ wq,
                                                    unsigned short* __restrict__ wp,
                                                    float* __restrict__ bias_s) {
    int gid = blockIdx.x * 256 + threadIdx.x;
    int i = gid * 4;
    if (i < 384 * 128) {
        int row = i >> 7;
        float sc = (row < 128) ? SCALE : 1.0f;
        float4 v = *(const float4*)&qkv_w[i];
        ushort4 pk;
        pk.x = f2bf(v.x * sc); pk.y = f2bf(v.y * sc);
        pk.z = f2bf(v.z * sc); pk.w = f2bf(v.w * sc);
        *(ushort4*)&wq[i] = pk;
    } else {
        int j = i - 384 * 128;
        float4 v = *(const float4*)&proj_w[j];
        ushort4 pk;
        pk.x = f2bf(v.x); pk.y = f2bf(v.y); pk.z = f2bf(v.z); pk.w = f2bf(v.w);
        *(ushort4*)&wp[j] = pk;
    }
    if (gid < 384) {
        bias_s[gid] = qkv_b[gid] * ((gid < 128) ? SCALE : 1.0f);
    }
}

// -------- Kernel 1: fused LayerNorm + QKV GEMM --------
// Block = 32 voxels. Barriers only in LN phase; GEMM phase: A from LDS,
// B-fragments loaded directly as bf16 (16B) from pre-converted wq. No conversion.
__global__ __launch_bounds__(256) void ln_qkv_kernel(const float* __restrict__ x,
                                                     const float* __restrict__ gamma,
                                                     const float* __restrict__ beta,
                                                     const unsigned short* __restrict__ wq,
                                                     const float* __restrict__ bias_s,
                                                     unsigned short* __restrict__ qkv) {
    __shared__ __align__(16) unsigned short a_s[32 * 136];  // 8.5 KB
    __shared__ float xs[128 * 33];                          // 16.9 KB
    __shared__ float g[128], bta[128];
    __shared__ float ps[256], pq[256];
    __shared__ float muS[32], rsS[32];

    int t = threadIdx.x;
    int v0 = blockIdx.x * 32;
    if (t < 128) { g[t] = gamma[t]; bta[t] = beta[t]; }
    int vv = t & 31, cq = t >> 5;           // cq in [0,8)
    #pragma unroll
    for (int cb = 0; cb < 16; cb++) {
        int c = cb * 8 + cq;
        xs[c * 33 + vv] = x[(size_t)c * N_VOX + v0 + vv];
    }
    __syncthreads();
    float s = 0.f, sq = 0.f;
    #pragma unroll
    for (int i = 0; i < 16; i++) {
        float val = xs[(cq * 16 + i) * 33 + vv];
        s += val; sq += val * val;
    }
    ps[t] = s; pq[t] = sq;
    __syncthreads();
    if (t < 32) {
        float S = 0.f, Q = 0.f;
        #pragma unroll
        for (int k = 0; k < 8; k++) { S += ps[t + k * 32]; Q += pq[t + k * 32]; }
        float mu = S * (1.0f / 128.0f);
        float var = Q * (1.0f / 128.0f) - mu * mu;
        muS[t] = mu; rsS[t] = rsqrtf(var + EPSV);
    }
    __syncthreads();
    {
        int c8 = t & 15;
        #pragma unroll
        for (int pass = 0; pass < 2; pass++) {
            int v = pass * 16 + (t >> 4);
            float mu = muS[v], rs = rsS[v];
            union { unsigned short u[8]; uint4 q; } pk;
            #pragma unroll
            for (int i = 0; i < 8; i++) {
                int c = c8 * 8 + i;
                float val = (xs[c * 33 + v] - mu) * rs * g[c] + bta[c];
                pk.u[i] = f2bf(val);
            }
            *(uint4*)&a_s[v * 136 + c8 * 8] = pk.q;
        }
    }
    __syncthreads();   // last barrier — GEMM phase is wave-independent

    int wave = t >> 6, lane = t & 63, m = lane & 15, quad = lane >> 4;
    int msub = wave & 1;            // which 16-voxel half of the block
    int sgrp = wave >> 1;           // strip group: 0 -> tiles 0-2, 1 -> 3-5

    for (int it = 0; it < 3; it++) {
        int o0 = (sgrp * 3 + it) * 64;
        ffrag acc[4] = {ffrag{0,0,0,0}, ffrag{0,0,0,0}, ffrag{0,0,0,0}, ffrag{0,0,0,0}};
        #pragma unroll
        for (int kk = 0; kk < 4; kk++) {
            bfrag a = *(bfrag*)&a_s[(msub * 16 + m) * 136 + kk * 32 + quad * 8];
            #pragma unroll
            for (int nt = 0; nt < 4; nt++) {
                bfrag bb = *(const bfrag*)&wq[(size_t)(o0 + nt * 16 + m) * 128 + kk * 32 + quad * 8];
                acc[nt] = __builtin_amdgcn_mfma_f32_16x16x32_bf16(a, bb, acc[nt], 0, 0, 0);
            }
        }
        #pragma unroll
        for (int nt = 0; nt < 4; nt++) {
            int o = o0 + nt * 16 + m;
            float bs = bias_s[o];
            int sec = o >> 7;
            int oc = o & 127;
            unsigned short* dst = qkv + (size_t)sec * ((size_t)N_VOX * 128);
            #pragma unroll
            for (int r = 0; r < 4; r++) {
                int vg = v0 + msub * 16 + quad * 4 + r;
                dst[(size_t)vg * 128 + oc] = f2bf(acc[nt][r] + bs);
            }
        }
    }
}

// -------- Kernel 2: neighborhood attention (packed 2 channels/lane) --------
// Lane l owns channels {2l, 2l+1}; head = l>>4; reduction group = 16 lanes.
// Scale is pre-folded into q. ob aliases qb (per-lane read-before-write).
__global__ __launch_bounds__(256) void attn_kernel(const unsigned int* __restrict__ qb,
                                                   const unsigned int* __restrict__ kb,
                                                   const unsigned int* __restrict__ vb,
                                                   unsigned int* __restrict__ ob) {
    int t = threadIdx.x;
    int wave = t >> 6, lane = t & 63;
    int v = blockIdx.x * 4 + wave;
    int z = v & 31, y = (v >> 5) & 31, x = v >> 10;
    int sx = min(max(x - 1, 0), 29);
    int sy = min(max(y - 1, 0), 29);
    int sz = min(max(z - 1, 0), 29);
    int base = (sx << 10) + (sy << 5) + sz;
    unsigned int qpk = qb[(size_t)v * 64 + lane];
    float q0 = bf2f_lo(qpk);
    float q1 = bf2f_hi(qpk);
    float s[27];
    unsigned int vpk[27];
    #pragma unroll
    for (int j = 0; j < 27; j++) {
        int jx = j / 9, jy = (j % 9) / 3, jz = j % 3;
        int vj = base + (jx << 10) + (jy << 5) + jz;
        size_t idx = (size_t)vj * 64 + lane;
        unsigned int kpk = kb[idx];
        vpk[j] = vb[idx];
        float p = q0 * bf2f_lo(kpk) + q1 * bf2f_hi(kpk);
        p += __shfl_xor(p, 8);
        p += __shfl_xor(p, 4);
        p += __shfl_xor(p, 2);
        p += __shfl_xor(p, 1);
        s[j] = p;
    }
    float mx = s[0];
    #pragma unroll
    for (int j = 1; j < 27; j++) mx = fmaxf(mx, s[j]);
    float sum = 0.f;
    #pragma unroll
    for (int j = 0; j < 27; j++) { s[j] = __expf(s[j] - mx); sum += s[j]; }
    float inv = 1.0f / sum;
    float o0 = 0.f, o1 = 0.f;
    #pragma unroll
    for (int j = 0; j < 27; j++) {
        o0 += s[j] * bf2f_lo(vpk[j]);
        o1 += s[j] * bf2f_hi(vpk[j]);
    }
    unsigned int opk = ((unsigned int)f2bf(o0 * inv)) | (((unsigned int)f2bf(o1 * inv)) << 16);
    ob[(size_t)v * 64 + lane] = opk;
}

// -------- Kernel 3: proj GEMM + bias + residual + transpose to (C, N) --------
// Block = 64 voxels. A staged once (1 barrier); B direct bf16 loads from wp.
__global__ __launch_bounds__(256) void proj_kernel(const unsigned short* __restrict__ a,
                                                   const unsigned short* __restrict__ wp,
                                                   const float* __restrict__ bias,
                                                   const float* __restrict__ xres,
                                                   float* __restrict__ out) {
    __shared__ __align__(16) unsigned short a_s[64 * 136];
    int t = threadIdx.x;
    int m0 = blockIdx.x * 64;
    int r4 = t >> 4, c8 = t & 15;
    #pragma unroll
    for (int pass = 0; pass < 4; pass++) {
        int r = pass * 16 + r4;
        *(uint4*)&a_s[r * 136 + c8 * 8] =
            *(const uint4*)&a[(size_t)(m0 + r) * 128 + c8 * 8];
    }
    __syncthreads();

    int wave = t >> 6, lane = t & 63, m = lane & 15, quad = lane >> 4;
    // wave handles m-subtile `wave`, both 64-col o-tiles
    for (int ot = 0; ot < 2; ot++) {
        int o0 = ot * 64;
        ffrag acc[4] = {ffrag{0,0,0,0}, ffrag{0,0,0,0}, ffrag{0,0,0,0}, ffrag{0,0,0,0}};
        #pragma unroll
        for (int kk = 0; kk < 4; kk++) {
            bfrag av = *(bfrag*)&a_s[(wave * 16 + m) * 136 + kk * 32 + quad * 8];
            #pragma unroll
            for (int nt = 0; nt < 4; nt++) {
                bfrag bb = *(const bfrag*)&wp[(size_t)(o0 + nt * 16 + m) * 128 + kk * 32 + quad * 8];
                acc[nt] = __builtin_amdgcn_mfma_f32_16x16x32_bf16(av, bb, acc[nt], 0, 0, 0);
            }
        }
        #pragma unroll
        for (int nt = 0; nt < 4; nt++) {
            int c = o0 + nt * 16 + m;
            float bs = bias[c];
            int vg = m0 + wave * 16 + quad * 4;
            float4 r = *(const float4*)&xres[(size_t)c * N_VOX + vg];
            float4 ov;
            ov.x = acc[nt][0] + bs + r.x;
            ov.y = acc[nt][1] + bs + r.y;
            ov.z = acc[nt][2] + bs + r.z;
            ov.w = acc[nt][3] + bs + r.w;
            *(float4*)&out[(size_t)c * N_VOX + vg] = ov;
        }
    }
}

extern "C" void kernel_launch(void* const* d_in, const int* in_sizes, int n_in,
                              void* d_out, int out_size, void* d_ws, size_t ws_size,
                              hipStream_t stream) {
    const float* x      = (const float*)d_in[0];
    const float* gamma  = (const float*)d_in[1];
    const float* beta   = (const float*)d_in[2];
    const float* qkv_w  = (const float*)d_in[3];
    const float* qkv_b  = (const float*)d_in[4];
    const float* proj_w = (const float*)d_in[5];
    const float* proj_b = (const float*)d_in[6];
    float* out = (float*)d_out;

    // ws: [0,24MB) qkv q|k|v; then wq (96KB), wp (32KB), bias_s (1.5KB)
    unsigned short* qkv  = (unsigned short*)d_ws;
    unsigned short* qb   = qkv;
    unsigned short* kb   = qkv + (size_t)N_VOX * 128;
    unsigned short* vb   = qkv + (size_t)2 * N_VOX * 128;
    unsigned short* wq   = (unsigned short*)((char*)d_ws + (24u << 20));
    unsigned short* wp   = wq + 384 * 128;
    float*          bias_s = (float*)(wp + 128 * 128);
    unsigned short* attn = qb;   // alias: attn output overwrites q

    hipLaunchKernelGGL(convw_kernel, dim3(64), dim3(256), 0, stream,
                       qkv_w, proj_w, qkv_b, wq, wp, bias_s);
    hipLaunchKernelGGL(ln_qkv_kernel, dim3(1024), dim3(256), 0, stream,
                       x, gamma, beta, wq, bias_s, qkv);
    hipLaunchKernelGGL(attn_kernel, dim3(8192), dim3(256), 0, stream,
                       (const unsigned int*)qb, (const unsigned int*)kb,
                       (const unsigned int*)vb, (unsigned int*)attn);
    hipLaunchKernelGGL(proj_kernel, dim3(512), dim3(256), 0, stream,
                       attn, wp, proj_b, x, out);
}

// Round 7
// 142.278 us; speedup vs baseline: 1.4404x; 1.1410x over previous
//
#include <hip/hip_runtime.h>

#define N_VOX 32768
#define EPSV 1e-5f
#define SCALE 0.17677669529663687f  // 32^-0.5

typedef __attribute__((ext_vector_type(8))) short bfrag;
typedef __attribute__((ext_vector_type(4))) float ffrag;

__device__ __forceinline__ float bf2f_lo(unsigned int u) {
    union { unsigned int i; float f; } c; c.i = u << 16; return c.f;
}
__device__ __forceinline__ float bf2f_hi(unsigned int u) {
    union { unsigned int i; float f; } c; c.i = u & 0xFFFF0000u; return c.f;
}
__device__ __forceinline__ unsigned short f2bf(float f) {
    union { float f; unsigned int i; } c; c.f = f;
    unsigned int i = c.i;
    return (unsigned short)((i + 0x7FFFu + ((i >> 16) & 1u)) >> 16);
}

// -------- Kernel 0: convert weights fp32 -> bf16 once; fold SCALE into q rows --------
__global__ __launch_bounds__(256) void convw_kernel(const float* __restrict__ qkv_w,
                                                    const float* __restrict__ proj_w,
                                                    const float* __restrict__ qkv_b,
                                                    unsigned short* __restrict__ wq,
                                                    unsigned short* __restrict__ wp,
                                                    float* __restrict__ bias_s) {
    int gid = blockIdx.x * 256 + threadIdx.x;
    int i = gid * 4;
    if (i < 384 * 128) {
        int row = i >> 7;
        float sc = (row < 128) ? SCALE : 1.0f;
        float4 v = *(const float4*)&qkv_w[i];
        ushort4 pk;
        pk.x = f2bf(v.x * sc); pk.y = f2bf(v.y * sc);
        pk.z = f2bf(v.z * sc); pk.w = f2bf(v.w * sc);
        *(ushort4*)&wq[i] = pk;
    } else {
        int j = i - 384 * 128;
        float4 v = *(const float4*)&proj_w[j];
        ushort4 pk;
        pk.x = f2bf(v.x); pk.y = f2bf(v.y); pk.z = f2bf(v.z); pk.w = f2bf(v.w);
        *(ushort4*)&wp[j] = pk;
    }
    if (gid < 384) {
        bias_s[gid] = qkv_b[gid] * ((gid < 128) ? SCALE : 1.0f);
    }
}

// -------- Kernel 1: fused LayerNorm + QKV GEMM --------
// Block = 64 voxels. LN -> a_s. GEMM: weights as MFMA arg0 (D rows = o-channels),
// voxels as arg1 (D cols) -> epilogue packs 4 consecutive o into one 8B store.
// B tiles ping-pong staged from pre-converted bf16 wq (pure uint4 copies).
__global__ __launch_bounds__(256) void ln_qkv_kernel(const float* __restrict__ x,
                                                     const float* __restrict__ gamma,
                                                     const float* __restrict__ beta,
                                                     const unsigned short* __restrict__ wq,
                                                     const float* __restrict__ bias_s,
                                                     unsigned short* __restrict__ qkv) {
    __shared__ __align__(16) unsigned short a_s[64 * 136];          // 17.4 KB
    __shared__ __align__(16) char pool[2 * 64 * 136 * 2];           // xs / b_s[2] union
    __shared__ float g[128], bta[128];
    __shared__ float ps[256], pq[256];
    __shared__ float muS[64], rsS[64];
    float* xs = (float*)pool;                                       // 128*65 floats
    unsigned short (*b_s)[64 * 136] = (unsigned short (*)[64 * 136])pool;

    int t = threadIdx.x;
    int v0 = blockIdx.x * 64;
    if (t < 128) { g[t] = gamma[t]; bta[t] = beta[t]; }
    int vv = t & 63, cq = t >> 6;
    for (int cb = 0; cb < 32; cb++) {
        int c = cb * 4 + cq;
        xs[c * 65 + vv] = x[(size_t)c * N_VOX + v0 + vv];
    }
    __syncthreads();
    float s = 0.f, sq = 0.f;
    for (int i = 0; i < 32; i++) {
        float val = xs[(cq * 32 + i) * 65 + vv];
        s += val; sq += val * val;
    }
    ps[t] = s; pq[t] = sq;
    __syncthreads();
    if (t < 64) {
        float S = ps[t] + ps[t + 64] + ps[t + 128] + ps[t + 192];
        float Q = pq[t] + pq[t + 64] + pq[t + 128] + pq[t + 192];
        float mu = S * (1.0f / 128.0f);
        float var = Q * (1.0f / 128.0f) - mu * mu;
        muS[t] = mu; rsS[t] = rsqrtf(var + EPSV);
    }
    __syncthreads();
    int r4 = t >> 4, c8 = t & 15;
    #pragma unroll
    for (int pass = 0; pass < 4; pass++) {
        int v = pass * 16 + r4;
        float mu = muS[v], rs = rsS[v];
        union { unsigned short u[8]; uint4 q; } pk;
        #pragma unroll
        for (int i = 0; i < 8; i++) {
            int c = c8 * 8 + i;
            float val = (xs[c * 65 + v] - mu) * rs * g[c] + bta[c];
            pk.u[i] = f2bf(val);
        }
        *(uint4*)&a_s[v * 136 + c8 * 8] = pk.q;
    }
    __syncthreads();   // xs dead; pool becomes b_s ping-pong

    int wave = t >> 6, lane = t & 63, m = lane & 15, quad = lane >> 4;

    // stage tile 0
    #pragma unroll
    for (int pass = 0; pass < 4; pass++) {
        int r = pass * 16 + r4;
        *(uint4*)&b_s[0][r * 136 + c8 * 8] = *(const uint4*)&wq[(size_t)r * 128 + c8 * 8];
    }
    __syncthreads();

    for (int ot = 0; ot < 6; ot++) {
        int buf = ot & 1;
        if (ot < 5) {
            int o0n = (ot + 1) * 64;
            #pragma unroll
            for (int pass = 0; pass < 4; pass++) {
                int r = pass * 16 + r4;
                *(uint4*)&b_s[buf ^ 1][r * 136 + c8 * 8] =
                    *(const uint4*)&wq[(size_t)(o0n + r) * 128 + c8 * 8];
            }
        }
        ffrag acc[4] = {ffrag{0,0,0,0}, ffrag{0,0,0,0}, ffrag{0,0,0,0}, ffrag{0,0,0,0}};
        #pragma unroll
        for (int kk = 0; kk < 4; kk++) {
            bfrag vf = *(bfrag*)&a_s[(wave * 16 + m) * 136 + kk * 32 + quad * 8];
            #pragma unroll
            for (int nt = 0; nt < 4; nt++) {
                bfrag wf = *(bfrag*)&b_s[buf][(nt * 16 + m) * 136 + kk * 32 + quad * 8];
                acc[nt] = __builtin_amdgcn_mfma_f32_16x16x32_bf16(wf, vf, acc[nt], 0, 0, 0);
            }
        }
        // epilogue: lane owns voxel v = v0+wave*16+m, o = ot*64 + nt*16 + quad*4 .. +3
        int sec = ot >> 1;
        int oloc = (ot & 1) * 64;
        unsigned short* dst = qkv + (size_t)sec * ((size_t)N_VOX * 128);
        int v = v0 + wave * 16 + m;
        #pragma unroll
        for (int nt = 0; nt < 4; nt++) {
            float4 bs4 = *(const float4*)&bias_s[ot * 64 + nt * 16 + quad * 4];
            ushort4 pk;
            pk.x = f2bf(acc[nt][0] + bs4.x);
            pk.y = f2bf(acc[nt][1] + bs4.y);
            pk.z = f2bf(acc[nt][2] + bs4.z);
            pk.w = f2bf(acc[nt][3] + bs4.w);
            *(ushort4*)&dst[(size_t)v * 128 + oloc + nt * 16 + quad * 4] = pk;
        }
        __syncthreads();
    }
}

// -------- Kernel 2: neighborhood attention (packed 2 channels/lane) --------
// Scale pre-folded into q. ob aliases qb (per-lane read-before-write).
__global__ __launch_bounds__(256) void attn_kernel(const unsigned int* __restrict__ qb,
                                                   const unsigned int* __restrict__ kb,
                                                   const unsigned int* __restrict__ vb,
                                                   unsigned int* __restrict__ ob) {
    int t = threadIdx.x;
    int wave = t >> 6, lane = t & 63;
    int v = blockIdx.x * 4 + wave;
    int z = v & 31, y = (v >> 5) & 31, x = v >> 10;
    int sx = min(max(x - 1, 0), 29);
    int sy = min(max(y - 1, 0), 29);
    int sz = min(max(z - 1, 0), 29);
    int base = (sx << 10) + (sy << 5) + sz;
    unsigned int qpk = qb[(size_t)v * 64 + lane];
    float q0 = bf2f_lo(qpk);
    float q1 = bf2f_hi(qpk);
    float s[27];
    unsigned int vpk[27];
    #pragma unroll
    for (int j = 0; j < 27; j++) {
        int jx = j / 9, jy = (j % 9) / 3, jz = j % 3;
        int vj = base + (jx << 10) + (jy << 5) + jz;
        size_t idx = (size_t)vj * 64 + lane;
        unsigned int kpk = kb[idx];
        vpk[j] = vb[idx];
        float p = q0 * bf2f_lo(kpk) + q1 * bf2f_hi(kpk);
        p += __shfl_xor(p, 8);
        p += __shfl_xor(p, 4);
        p += __shfl_xor(p, 2);
        p += __shfl_xor(p, 1);
        s[j] = p;
    }
    float mx = s[0];
    #pragma unroll
    for (int j = 1; j < 27; j++) mx = fmaxf(mx, s[j]);
    float sum = 0.f;
    #pragma unroll
    for (int j = 0; j < 27; j++) { s[j] = __expf(s[j] - mx); sum += s[j]; }
    float inv = 1.0f / sum;
    float o0 = 0.f, o1 = 0.f;
    #pragma unroll
    for (int j = 0; j < 27; j++) {
        o0 += s[j] * bf2f_lo(vpk[j]);
        o1 += s[j] * bf2f_hi(vpk[j]);
    }
    unsigned int opk = ((unsigned int)f2bf(o0 * inv)) | (((unsigned int)f2bf(o1 * inv)) << 16);
    ob[(size_t)v * 64 + lane] = opk;
}

// -------- Kernel 3: proj GEMM + bias + residual + transpose to (C, N) --------
// Block = 64 voxels. A staged once; both wp tiles ping-pong staged in LDS.
// Voxels as arg0 (D rows = voxels) -> float4 epilogue along v.
__global__ __launch_bounds__(256) void proj_kernel(const unsigned short* __restrict__ a,
                                                   const unsigned short* __restrict__ wp,
                                                   const float* __restrict__ bias,
                                                   const float* __restrict__ xres,
                                                   float* __restrict__ out) {
    __shared__ __align__(16) unsigned short a_s[64 * 136];
    __shared__ __align__(16) unsigned short b_s[2][64 * 136];
    int t = threadIdx.x;
    int m0 = blockIdx.x * 64;
    int r4 = t >> 4, c8 = t & 15;
    #pragma unroll
    for (int pass = 0; pass < 4; pass++) {
        int r = pass * 16 + r4;
        *(uint4*)&a_s[r * 136 + c8 * 8] =
            *(const uint4*)&a[(size_t)(m0 + r) * 128 + c8 * 8];
        *(uint4*)&b_s[0][r * 136 + c8 * 8] =
            *(const uint4*)&wp[(size_t)r * 128 + c8 * 8];
    }
    __syncthreads();

    int wave = t >> 6, lane = t & 63, m = lane & 15, quad = lane >> 4;
    for (int ot = 0; ot < 2; ot++) {
        if (ot == 0) {
            #pragma unroll
            for (int pass = 0; pass < 4; pass++) {
                int r = pass * 16 + r4;
                *(uint4*)&b_s[1][r * 136 + c8 * 8] =
                    *(const uint4*)&wp[(size_t)(64 + r) * 128 + c8 * 8];
            }
        }
        int o0 = ot * 64;
        ffrag acc[4] = {ffrag{0,0,0,0}, ffrag{0,0,0,0}, ffrag{0,0,0,0}, ffrag{0,0,0,0}};
        #pragma unroll
        for (int kk = 0; kk < 4; kk++) {
            bfrag av = *(bfrag*)&a_s[(wave * 16 + m) * 136 + kk * 32 + quad * 8];
            #pragma unroll
            for (int nt = 0; nt < 4; nt++) {
                bfrag bb = *(bfrag*)&b_s[ot][(nt * 16 + m) * 136 + kk * 32 + quad * 8];
                acc[nt] = __builtin_amdgcn_mfma_f32_16x16x32_bf16(av, bb, acc[nt], 0, 0, 0);
            }
        }
        #pragma unroll
        for (int nt = 0; nt < 4; nt++) {
            int c = o0 + nt * 16 + m;
            float bs = bias[c];
            int vg = m0 + wave * 16 + quad * 4;
            float4 r = *(const float4*)&xres[(size_t)c * N_VOX + vg];
            float4 ov;
            ov.x = acc[nt][0] + bs + r.x;
            ov.y = acc[nt][1] + bs + r.y;
            ov.z = acc[nt][2] + bs + r.z;
            ov.w = acc[nt][3] + bs + r.w;
            *(float4*)&out[(size_t)c * N_VOX + vg] = ov;
        }
        __syncthreads();
    }
}

extern "C" void kernel_launch(void* const* d_in, const int* in_sizes, int n_in,
                              void* d_out, int out_size, void* d_ws, size_t ws_size,
                              hipStream_t stream) {
    const float* x      = (const float*)d_in[0];
    const float* gamma  = (const float*)d_in[1];
    const float* beta   = (const float*)d_in[2];
    const float* qkv_w  = (const float*)d_in[3];
    const float* qkv_b  = (const float*)d_in[4];
    const float* proj_w = (const float*)d_in[5];
    const float* proj_b = (const float*)d_in[6];
    float* out = (float*)d_out;

    // ws: [0,24MB) qkv q|k|v; then wq (96KB), wp (32KB), bias_s (1.5KB)
    unsigned short* qkv  = (unsigned short*)d_ws;
    unsigned short* qb   = qkv;
    unsigned short* kb   = qkv + (size_t)N_VOX * 128;
    unsigned short* vb   = qkv + (size_t)2 * N_VOX * 128;
    unsigned short* wq   = (unsigned short*)((char*)d_ws + (24u << 20));
    unsigned short* wp   = wq + 384 * 128;
    float*          bias_s = (float*)(wp + 128 * 128);
    unsigned short* attn = qb;   // alias: attn output overwrites q

    hipLaunchKernelGGL(convw_kernel, dim3(64), dim3(256), 0, stream,
                       qkv_w, proj_w, qkv_b, wq, wp, bias_s);
    hipLaunchKernelGGL(ln_qkv_kernel, dim3(512), dim3(256), 0, stream,
                       x, gamma, beta, wq, bias_s, qkv);
    hipLaunchKernelGGL(attn_kernel, dim3(8192), dim3(256), 0, stream,
                       (const unsigned int*)qb, (const unsigned int*)kb,
                       (const unsigned int*)vb, (unsigned int*)attn);
    hipLaunchKernelGGL(proj_kernel, dim3(512), dim3(256), 0, stream,
                       attn, wp, proj_b, x, out);
}

// Round 8
// 139.500 us; speedup vs baseline: 1.4690x; 1.0199x over previous
//
#include <hip/hip_runtime.h>

#define N_VOX 32768
#define EPSV 1e-5f
#define SCALE 0.17677669529663687f  // 32^-0.5

typedef __attribute__((ext_vector_type(8))) short bfrag;
typedef __attribute__((ext_vector_type(4))) float ffrag;

__device__ __forceinline__ float bf2f_lo(unsigned int u) {
    union { unsigned int i; float f; } c; c.i = u << 16; return c.f;
}
__device__ __forceinline__ float bf2f_hi(unsigned int u) {
    union { unsigned int i; float f; } c; c.i = u & 0xFFFF0000u; return c.f;
}
__device__ __forceinline__ unsigned short f2bf(float f) {
    union { float f; unsigned int i; } c; c.f = f;
    unsigned int i = c.i;
    return (unsigned short)((i + 0x7FFFu + ((i >> 16) & 1u)) >> 16);
}

// -------- Kernel 0: convert weights fp32 -> bf16 once; fold SCALE into q rows --------
__global__ __launch_bounds__(256) void convw_kernel(const float* __restrict__ qkv_w,
                                                    const float* __restrict__ proj_w,
                                                    const float* __restrict__ qkv_b,
                                                    unsigned short* __restrict__ wq,
                                                    unsigned short* __restrict__ wp,
                                                    float* __restrict__ bias_s) {
    int gid = blockIdx.x * 256 + threadIdx.x;
    int i = gid * 4;
    if (i < 384 * 128) {
        int row = i >> 7;
        float sc = (row < 128) ? SCALE : 1.0f;
        float4 v = *(const float4*)&qkv_w[i];
        ushort4 pk;
        pk.x = f2bf(v.x * sc); pk.y = f2bf(v.y * sc);
        pk.z = f2bf(v.z * sc); pk.w = f2bf(v.w * sc);
        *(ushort4*)&wq[i] = pk;
    } else {
        int j = i - 384 * 128;
        float4 v = *(const float4*)&proj_w[j];
        ushort4 pk;
        pk.x = f2bf(v.x); pk.y = f2bf(v.y); pk.z = f2bf(v.z); pk.w = f2bf(v.w);
        *(ushort4*)&wp[j] = pk;
    }
    if (gid < 384) {
        bias_s[gid] = qkv_b[gid] * ((gid < 128) ? SCALE : 1.0f);
    }
}

// -------- Kernel 1: fused LayerNorm + QKV GEMM --------
// Epilogue: per-wave LDS transpose -> full-cache-line coalesced qkv stores.
__global__ __launch_bounds__(256) void ln_qkv_kernel(const float* __restrict__ x,
                                                     const float* __restrict__ gamma,
                                                     const float* __restrict__ beta,
                                                     const unsigned short* __restrict__ wq,
                                                     const float* __restrict__ bias_s,
                                                     unsigned short* __restrict__ qkv) {
    __shared__ __align__(16) unsigned short a_s[64 * 136];          // 17.4 KB
    __shared__ __align__(16) char pool[2 * 64 * 136 * 2];           // xs / b_s[2] union
    __shared__ __align__(16) unsigned short trs_s[4 * 16 * 72];     // 9.2 KB, per-wave
    __shared__ float g[128], bta[128];
    __shared__ float ps[256], pq[256];
    __shared__ float muS[64], rsS[64];
    float* xs = (float*)pool;                                       // 128*65 floats
    unsigned short (*b_s)[64 * 136] = (unsigned short (*)[64 * 136])pool;

    int t = threadIdx.x;
    int v0 = blockIdx.x * 64;
    if (t < 128) { g[t] = gamma[t]; bta[t] = beta[t]; }
    int vv = t & 63, cq = t >> 6;
    for (int cb = 0; cb < 32; cb++) {
        int c = cb * 4 + cq;
        xs[c * 65 + vv] = x[(size_t)c * N_VOX + v0 + vv];
    }
    __syncthreads();
    float s = 0.f, sq = 0.f;
    for (int i = 0; i < 32; i++) {
        float val = xs[(cq * 32 + i) * 65 + vv];
        s += val; sq += val * val;
    }
    ps[t] = s; pq[t] = sq;
    __syncthreads();
    if (t < 64) {
        float S = ps[t] + ps[t + 64] + ps[t + 128] + ps[t + 192];
        float Q = pq[t] + pq[t + 64] + pq[t + 128] + pq[t + 192];
        float mu = S * (1.0f / 128.0f);
        float var = Q * (1.0f / 128.0f) - mu * mu;
        muS[t] = mu; rsS[t] = rsqrtf(var + EPSV);
    }
    __syncthreads();
    int r4 = t >> 4, c8 = t & 15;
    #pragma unroll
    for (int pass = 0; pass < 4; pass++) {
        int v = pass * 16 + r4;
        float mu = muS[v], rs = rsS[v];
        union { unsigned short u[8]; uint4 q; } pk;
        #pragma unroll
        for (int i = 0; i < 8; i++) {
            int c = c8 * 8 + i;
            float val = (xs[c * 65 + v] - mu) * rs * g[c] + bta[c];
            pk.u[i] = f2bf(val);
        }
        *(uint4*)&a_s[v * 136 + c8 * 8] = pk.q;
    }
    __syncthreads();   // xs dead; pool becomes b_s ping-pong

    int wave = t >> 6, lane = t & 63, m = lane & 15, quad = lane >> 4;
    unsigned short* trs = &trs_s[wave * (16 * 72)];

    // stage tile 0
    #pragma unroll
    for (int pass = 0; pass < 4; pass++) {
        int r = pass * 16 + r4;
        *(uint4*)&b_s[0][r * 136 + c8 * 8] = *(const uint4*)&wq[(size_t)r * 128 + c8 * 8];
    }
    __syncthreads();

    for (int ot = 0; ot < 6; ot++) {
        int buf = ot & 1;
        if (ot < 5) {
            int o0n = (ot + 1) * 64;
            #pragma unroll
            for (int pass = 0; pass < 4; pass++) {
                int r = pass * 16 + r4;
                *(uint4*)&b_s[buf ^ 1][r * 136 + c8 * 8] =
                    *(const uint4*)&wq[(size_t)(o0n + r) * 128 + c8 * 8];
            }
        }
        ffrag acc[4] = {ffrag{0,0,0,0}, ffrag{0,0,0,0}, ffrag{0,0,0,0}, ffrag{0,0,0,0}};
        #pragma unroll
        for (int kk = 0; kk < 4; kk++) {
            bfrag vf = *(bfrag*)&a_s[(wave * 16 + m) * 136 + kk * 32 + quad * 8];
            #pragma unroll
            for (int nt = 0; nt < 4; nt++) {
                bfrag wf = *(bfrag*)&b_s[buf][(nt * 16 + m) * 136 + kk * 32 + quad * 8];
                acc[nt] = __builtin_amdgcn_mfma_f32_16x16x32_bf16(wf, vf, acc[nt], 0, 0, 0);
            }
        }
        // epilogue: per-wave LDS transpose (lane owns voxel m, o = nt*16+quad*4..+3)
        #pragma unroll
        for (int nt = 0; nt < 4; nt++) {
            float4 bs4 = *(const float4*)&bias_s[ot * 64 + nt * 16 + quad * 4];
            ushort4 pk;
            pk.x = f2bf(acc[nt][0] + bs4.x);
            pk.y = f2bf(acc[nt][1] + bs4.y);
            pk.z = f2bf(acc[nt][2] + bs4.z);
            pk.w = f2bf(acc[nt][3] + bs4.w);
            *(ushort4*)&trs[m * 72 + nt * 16 + quad * 4] = pk;
        }
        // within-wave readback: 8 consecutive lanes cover 128 contiguous bytes
        int sec = ot >> 1;
        int oloc = (ot & 1) * 64;
        unsigned short* dst = qkv + (size_t)sec * ((size_t)N_VOX * 128);
        #pragma unroll
        for (int pass = 0; pass < 2; pass++) {
            int vl = pass * 8 + (lane >> 3);
            int part = lane & 7;
            uint4 val = *(uint4*)&trs[vl * 72 + part * 8];
            int v = v0 + wave * 16 + vl;
            *(uint4*)&dst[(size_t)v * 128 + oloc + part * 8] = val;
        }
        __syncthreads();
    }
}

// -------- Kernel 2: neighborhood attention (packed 2 channels/lane) --------
// Scale pre-folded into q. ob aliases qb (per-lane read-before-write).
__global__ __launch_bounds__(256) void attn_kernel(const unsigned int* __restrict__ qb,
                                                   const unsigned int* __restrict__ kb,
                                                   const unsigned int* __restrict__ vb,
                                                   unsigned int* __restrict__ ob) {
    int t = threadIdx.x;
    int wave = t >> 6, lane = t & 63;
    int v = blockIdx.x * 4 + wave;
    int z = v & 31, y = (v >> 5) & 31, x = v >> 10;
    int sx = min(max(x - 1, 0), 29);
    int sy = min(max(y - 1, 0), 29);
    int sz = min(max(z - 1, 0), 29);
    int base = (sx << 10) + (sy << 5) + sz;
    unsigned int qpk = qb[(size_t)v * 64 + lane];
    float q0 = bf2f_lo(qpk);
    float q1 = bf2f_hi(qpk);
    float s[27];
    unsigned int vpk[27];
    #pragma unroll
    for (int j = 0; j < 27; j++) {
        int jx = j / 9, jy = (j % 9) / 3, jz = j % 3;
        int vj = base + (jx << 10) + (jy << 5) + jz;
        size_t idx = (size_t)vj * 64 + lane;
        unsigned int kpk = kb[idx];
        vpk[j] = vb[idx];
        float p = q0 * bf2f_lo(kpk) + q1 * bf2f_hi(kpk);
        p += __shfl_xor(p, 8);
        p += __shfl_xor(p, 4);
        p += __shfl_xor(p, 2);
        p += __shfl_xor(p, 1);
        s[j] = p;
    }
    float mx = s[0];
    #pragma unroll
    for (int j = 1; j < 27; j++) mx = fmaxf(mx, s[j]);
    float sum = 0.f;
    #pragma unroll
    for (int j = 0; j < 27; j++) { s[j] = __expf(s[j] - mx); sum += s[j]; }
    float inv = 1.0f / sum;
    float o0 = 0.f, o1 = 0.f;
    #pragma unroll
    for (int j = 0; j < 27; j++) {
        o0 += s[j] * bf2f_lo(vpk[j]);
        o1 += s[j] * bf2f_hi(vpk[j]);
    }
    unsigned int opk = ((unsigned int)f2bf(o0 * inv)) | (((unsigned int)f2bf(o1 * inv)) << 16);
    ob[(size_t)v * 64 + lane] = opk;
}

// -------- Kernel 3: proj GEMM + bias + residual + transpose to (C, N) --------
__global__ __launch_bounds__(256) void proj_kernel(const unsigned short* __restrict__ a,
                                                   const unsigned short* __restrict__ wp,
                                                   const float* __restrict__ bias,
                                                   const float* __restrict__ xres,
                                                   float* __restrict__ out) {
    __shared__ __align__(16) unsigned short a_s[64 * 136];
    __shared__ __align__(16) unsigned short b_s[2][64 * 136];
    int t = threadIdx.x;
    int m0 = blockIdx.x * 64;
    int r4 = t >> 4, c8 = t & 15;
    #pragma unroll
    for (int pass = 0; pass < 4; pass++) {
        int r = pass * 16 + r4;
        *(uint4*)&a_s[r * 136 + c8 * 8] =
            *(const uint4*)&a[(size_t)(m0 + r) * 128 + c8 * 8];
        *(uint4*)&b_s[0][r * 136 + c8 * 8] =
            *(const uint4*)&wp[(size_t)r * 128 + c8 * 8];
    }
    __syncthreads();

    int wave = t >> 6, lane = t & 63, m = lane & 15, quad = lane >> 4;
    for (int ot = 0; ot < 2; ot++) {
        if (ot == 0) {
            #pragma unroll
            for (int pass = 0; pass < 4; pass++) {
                int r = pass * 16 + r4;
                *(uint4*)&b_s[1][r * 136 + c8 * 8] =
                    *(const uint4*)&wp[(size_t)(64 + r) * 128 + c8 * 8];
            }
        }
        int o0 = ot * 64;
        ffrag acc[4] = {ffrag{0,0,0,0}, ffrag{0,0,0,0}, ffrag{0,0,0,0}, ffrag{0,0,0,0}};
        #pragma unroll
        for (int kk = 0; kk < 4; kk++) {
            bfrag av = *(bfrag*)&a_s[(wave * 16 + m) * 136 + kk * 32 + quad * 8];
            #pragma unroll
            for (int nt = 0; nt < 4; nt++) {
                bfrag bb = *(bfrag*)&b_s[ot][(nt * 16 + m) * 136 + kk * 32 + quad * 8];
                acc[nt] = __builtin_amdgcn_mfma_f32_16x16x32_bf16(av, bb, acc[nt], 0, 0, 0);
            }
        }
        #pragma unroll
        for (int nt = 0; nt < 4; nt++) {
            int c = o0 + nt * 16 + m;
            float bs = bias[c];
            int vg = m0 + wave * 16 + quad * 4;
            float4 r = *(const float4*)&xres[(size_t)c * N_VOX + vg];
            float4 ov;
            ov.x = acc[nt][0] + bs + r.x;
            ov.y = acc[nt][1] + bs + r.y;
            ov.z = acc[nt][2] + bs + r.z;
            ov.w = acc[nt][3] + bs + r.w;
            *(float4*)&out[(size_t)c * N_VOX + vg] = ov;
        }
        __syncthreads();
    }
}

extern "C" void kernel_launch(void* const* d_in, const int* in_sizes, int n_in,
                              void* d_out, int out_size, void* d_ws, size_t ws_size,
                              hipStream_t stream) {
    const float* x      = (const float*)d_in[0];
    const float* gamma  = (const float*)d_in[1];
    const float* beta   = (const float*)d_in[2];
    const float* qkv_w  = (const float*)d_in[3];
    const float* qkv_b  = (const float*)d_in[4];
    const float* proj_w = (const float*)d_in[5];
    const float* proj_b = (const float*)d_in[6];
    float* out = (float*)d_out;

    // ws: [0,24MB) qkv q|k|v; then wq (96KB), wp (32KB), bias_s (1.5KB)
    unsigned short* qkv  = (unsigned short*)d_ws;
    unsigned short* qb   = qkv;
    unsigned short* kb   = qkv + (size_t)N_VOX * 128;
    unsigned short* vb   = qkv + (size_t)2 * N_VOX * 128;
    unsigned short* wq   = (unsigned short*)((char*)d_ws + (24u << 20));
    unsigned short* wp   = wq + 384 * 128;
    float*          bias_s = (float*)(wp + 128 * 128);
    unsigned short* attn = qb;   // alias: attn output overwrites q

    hipLaunchKernelGGL(convw_kernel, dim3(64), dim3(256), 0, stream,
                       qkv_w, proj_w, qkv_b, wq, wp, bias_s);
    hipLaunchKernelGGL(ln_qkv_kernel, dim3(512), dim3(256), 0, stream,
                       x, gamma, beta, wq, bias_s, qkv);
    hipLaunchKernelGGL(attn_kernel, dim3(8192), dim3(256), 0, stream,
                       (const unsigned int*)qb, (const unsigned int*)kb,
                       (const unsigned int*)vb, (unsigned int*)attn);
    hipLaunchKernelGGL(proj_kernel, dim3(512), dim3(256), 0, stream,
                       attn, wp, proj_b, x, out);
}